// Round 5
// baseline (2786.595 us; speedup 1.0000x reference)
//
#include <hip/hip_runtime.h>

#define FD 96
#define QD 24      // FD/4 float4s per row
#define MMGRID 512

// ---------------- CSR build ----------------

__global__ void k_degree(const int* __restrict__ dst, int* __restrict__ deg, int E) {
    int e = blockIdx.x * blockDim.x + threadIdx.x;
    if (e < E) atomicAdd(&deg[dst[e]], 1);
}

__global__ void k_rowptr(const int* __restrict__ deg, int* __restrict__ row_ptr,
                         int* __restrict__ cursor, float* __restrict__ inv_deg,
                         int* __restrict__ counter, int n) {
    int i = blockIdx.x * blockDim.x + threadIdx.x;
    int v = (i < n) ? deg[i] : 0;
    int lane = threadIdx.x & 63;
    int incl = v;
    #pragma unroll
    for (int off = 1; off < 64; off <<= 1) {
        int t = __shfl_up(incl, off, 64);
        if (lane >= off) incl += t;
    }
    int waveTot = __shfl(incl, 63, 64);
    int base = 0;
    if (lane == 63) base = atomicAdd(counter, waveTot);
    base = __shfl(base, 63, 64);
    int excl = incl - v;
    if (i < n) {
        int start = base + excl;
        row_ptr[i] = start;
        cursor[i]  = start;
        inv_deg[i] = (v > 0) ? (1.0f / (float)v) : 0.0f;
    }
}

__global__ void k_fill(const int* __restrict__ src, const int* __restrict__ dst,
                       int* __restrict__ cursor, int* __restrict__ csr, int E) {
    int e = blockIdx.x * blockDim.x + threadIdx.x;
    if (e < E) {
        int p = atomicAdd(&cursor[dst[e]], 1);
        csr[p] = src[e];
    }
}

// ---------------- aggregation: t = nrm(self) + inv_deg * sum nrm(nbr) ----------------

__device__ __forceinline__ float4 nrm4(float4 x, float4 a, float4 c) {
    float4 r;
    r.x = fmaxf(fmaf(a.x, x.x, c.x), 0.f);
    r.y = fmaxf(fmaf(a.y, x.y, c.y), 0.f);
    r.z = fmaxf(fmaf(a.z, x.z, c.z), 0.f);
    r.w = fmaxf(fmaf(a.w, x.w, c.w), 0.f);
    return r;
}

template<int NORM>
__global__ __launch_bounds__(256, 4) void k_agg(
    const float4* __restrict__ hin4,
    const int* __restrict__ rp, const int* __restrict__ re,
    const int* __restrict__ csr, const float* __restrict__ invd,
    const float* __restrict__ nA, const float* __restrict__ nC,
    float4* __restrict__ t4, int n)
{
    int g = blockIdx.x * blockDim.x + threadIdx.x;
    int node = g / QD;
    if (node >= n) return;
    int q = g - node * QD;
    float4 a = make_float4(0.f, 0.f, 0.f, 0.f), c = a;
    if (NORM) { a = ((const float4*)nA)[q]; c = ((const float4*)nC)[q]; }
    int e = rp[node];
    const int end = re[node];
    float ax = 0.f, ay = 0.f, az = 0.f, aw = 0.f;
    for (; e + 8 <= end; e += 8) {
        int n0 = csr[e],     n1 = csr[e + 1], n2 = csr[e + 2], n3 = csr[e + 3];
        int n4 = csr[e + 4], n5 = csr[e + 5], n6 = csr[e + 6], n7 = csr[e + 7];
        float4 x0 = hin4[(size_t)n0 * QD + q];
        float4 x1 = hin4[(size_t)n1 * QD + q];
        float4 x2 = hin4[(size_t)n2 * QD + q];
        float4 x3 = hin4[(size_t)n3 * QD + q];
        float4 x4 = hin4[(size_t)n4 * QD + q];
        float4 x5 = hin4[(size_t)n5 * QD + q];
        float4 x6 = hin4[(size_t)n6 * QD + q];
        float4 x7 = hin4[(size_t)n7 * QD + q];
        if (NORM) {
            x0 = nrm4(x0, a, c); x1 = nrm4(x1, a, c); x2 = nrm4(x2, a, c); x3 = nrm4(x3, a, c);
            x4 = nrm4(x4, a, c); x5 = nrm4(x5, a, c); x6 = nrm4(x6, a, c); x7 = nrm4(x7, a, c);
        }
        ax += (x0.x + x1.x) + (x2.x + x3.x) + ((x4.x + x5.x) + (x6.x + x7.x));
        ay += (x0.y + x1.y) + (x2.y + x3.y) + ((x4.y + x5.y) + (x6.y + x7.y));
        az += (x0.z + x1.z) + (x2.z + x3.z) + ((x4.z + x5.z) + (x6.z + x7.z));
        aw += (x0.w + x1.w) + (x2.w + x3.w) + ((x4.w + x5.w) + (x6.w + x7.w));
    }
    for (; e < end; e++) {
        int nb = csr[e];
        float4 x = hin4[(size_t)nb * QD + q];
        if (NORM) x = nrm4(x, a, c);
        ax += x.x; ay += x.y; az += x.z; aw += x.w;
    }
    float4 s = hin4[(size_t)node * QD + q];
    if (NORM) s = nrm4(s, a, c);
    float id = invd[node];
    float4 o;
    o.x = fmaf(id, ax, s.x);
    o.y = fmaf(id, ay, s.y);
    o.z = fmaf(id, az, s.z);
    o.w = fmaf(id, aw, s.w);
    t4[(size_t)node * QD + q] = o;
}

// ---------------- matmul: out = t @ W + b, W staged in LDS ----------------
// block 192 = (f:96) x (g:2). Subgroup g computes its own 8-node tile; W shared in LDS.
// Per k-chunk(4): 4 conflict-free ds_read_b32 (W) + 8 ds_read_b128 broadcasts (t) + 32 FMA.

template<int STATS>
__global__ __launch_bounds__(192, 2) void k_mm(
    const float* __restrict__ tin, const float* __restrict__ W,
    const float* __restrict__ bias, float* __restrict__ out,
    float* __restrict__ acc, int n)
{
    __shared__ float Wl[FD * FD];
    __shared__ __align__(16) float tl[2][8][FD];
    const int tid = threadIdx.x;
    const int f = tid % FD;      // output column
    const int g = tid / FD;      // tile subgroup 0/1
    // stage W: 9216 floats = 2304 float4
    #pragma unroll
    for (int i = 0; i < 12; i++)
        ((float4*)Wl)[tid + 192 * i] = ((const float4*)W)[tid + 192 * i];
    const float bf = bias[f];
    float s = 0.f, s2 = 0.f;
    const int npairs = (n + 15) / 16;

    for (int p = blockIdx.x; p < npairs; p += gridDim.x) {
        const int base = p * 16;       // 16 nodes = 2 tiles of 8
        const float4* src4 = (const float4*)(tin + (size_t)base * FD);
        const int lim4 = (n - base >= 16 ? 16 : n - base) * QD;
        #pragma unroll
        for (int i = 0; i < 2; i++) {
            int idx = tid + 192 * i;
            ((float4*)tl)[idx] = (idx < lim4) ? src4[idx] : make_float4(0.f, 0.f, 0.f, 0.f);
        }
        __syncthreads();
        float o[8];
        #pragma unroll
        for (int j = 0; j < 8; j++) o[j] = 0.f;
        #pragma unroll
        for (int kc = 0; kc < FD; kc += 4) {
            float w0 = Wl[(kc + 0) * FD + f];
            float w1 = Wl[(kc + 1) * FD + f];
            float w2 = Wl[(kc + 2) * FD + f];
            float w3 = Wl[(kc + 3) * FD + f];
            #pragma unroll
            for (int j = 0; j < 8; j++) {
                float4 tv = *(const float4*)(&tl[g][j][kc]);   // LDS broadcast
                o[j] = fmaf(tv.w, w3, fmaf(tv.z, w2, fmaf(tv.y, w1, fmaf(tv.x, w0, o[j]))));
            }
        }
        const int nodeb = base + g * 8;
        #pragma unroll
        for (int j = 0; j < 8; j++) {
            if (nodeb + j < n) {
                float v = o[j] + bf;
                out[(size_t)(nodeb + j) * FD + f] = v;
                if (STATS) { s += v; s2 = fmaf(v, v, s2); }
            }
        }
        __syncthreads();
    }
    if (STATS) {
        atomicAdd(&acc[f], s);
        atomicAdd(&acc[FD + f], s2);
    }
}

// BN constants: a = gamma*rsqrt(var+eps), c = beta - mu*a  (1 block, FD threads)
__global__ void k_bnfin(const float* __restrict__ acc,
                        const float* __restrict__ gamma, const float* __restrict__ beta,
                        float* __restrict__ na, float* __restrict__ nc, float invN) {
    int f = threadIdx.x;
    float mu  = acc[f] * invN;
    float var = acc[FD + f] * invN - mu * mu;
    float a = gamma[f] * rsqrtf(var + 1e-5f);
    na[f] = a;
    nc[f] = beta[f] - mu * a;
}

extern "C" void kernel_launch(void* const* d_in, const int* in_sizes, int n_in,
                              void* d_out, int out_size, void* d_ws, size_t ws_size,
                              hipStream_t stream) {
    const float* feat = (const float*)d_in[0];
    const float* W1   = (const float*)d_in[1];
    const float* b1   = (const float*)d_in[2];
    const float* g1   = (const float*)d_in[3];
    const float* be1  = (const float*)d_in[4];
    const float* W2   = (const float*)d_in[5];
    const float* b2   = (const float*)d_in[6];
    const float* g2   = (const float*)d_in[7];
    const float* be2  = (const float*)d_in[8];
    const float* W3   = (const float*)d_in[9];
    const float* b3   = (const float*)d_in[10];
    const int*   src  = (const int*)d_in[11];
    const int*   dst  = (const int*)d_in[12];

    const int n = in_sizes[0] / FD;   // 50000
    const int e = in_sizes[11];       // 800000

    char* w = (char*)d_ws;
    float* A       = (float*)w; w += (size_t)n * FD * 4;
    int*   deg     = (int*)w;   w += (size_t)n * 4;
    int*   counter = (int*)w;   w += 4;
    float* acc1    = (float*)w; w += 2 * FD * 4;   // zeroed together with deg
    float* acc2    = (float*)w; w += 2 * FD * 4;
    int*   rp      = (int*)w;   w += (size_t)n * 4;
    int*   re      = (int*)w;   w += (size_t)n * 4;
    int*   csr     = (int*)w;   w += (size_t)e * 4;
    float* invd    = (float*)w; w += (size_t)n * 4;
    float* na1     = (float*)w; w += FD * 4;
    float* nc1     = (float*)w; w += FD * 4;
    float* na2     = (float*)w; w += FD * 4;
    float* nc2     = (float*)w; w += FD * 4;

    float* O = (float*)d_out;
    const float invN = 1.0f / (float)n;
    const int AGG_GRID = (n * QD + 255) / 256;

    hipMemsetAsync(deg, 0, (size_t)(n + 1 + 4 * FD) * 4, stream);
    k_degree<<<(e + 255) / 256, 256, 0, stream>>>(dst, deg, e);
    k_rowptr<<<(n + 255) / 256, 256, 0, stream>>>(deg, rp, re, invd, counter, n);
    k_fill  <<<(e + 255) / 256, 256, 0, stream>>>(src, dst, re, csr, e);

    // layer 1
    k_agg<0><<<AGG_GRID, 256, 0, stream>>>((const float4*)feat, rp, re, csr, invd,
                                           nullptr, nullptr, (float4*)A, n);
    k_mm<1><<<MMGRID, 192, 0, stream>>>(A, W1, b1, A, acc1, n);
    k_bnfin<<<1, FD, 0, stream>>>(acc1, g1, be1, na1, nc1, invN);

    // layer 2
    k_agg<1><<<AGG_GRID, 256, 0, stream>>>((const float4*)A, rp, re, csr, invd,
                                           na1, nc1, (float4*)O, n);
    k_mm<1><<<MMGRID, 192, 0, stream>>>(O, W2, b2, O, acc2, n);
    k_bnfin<<<1, FD, 0, stream>>>(acc2, g2, be2, na2, nc2, invN);

    // layer 3
    k_agg<1><<<AGG_GRID, 256, 0, stream>>>((const float4*)O, rp, re, csr, invd,
                                           na2, nc2, (float4*)A, n);
    k_mm<0><<<MMGRID, 192, 0, stream>>>(A, W3, b3, O, nullptr, n);
}

// Round 6
// 397.400 us; speedup vs baseline: 7.0121x; 7.0121x over previous
//
#include <hip/hip_runtime.h>

#define FD 96
#define QD 24      // FD/4 float4s per row
#define MMGRID 512

// ---------------- CSR build ----------------

__global__ void k_degree(const int* __restrict__ dst, int* __restrict__ deg, int E) {
    int e = blockIdx.x * blockDim.x + threadIdx.x;
    if (e < E) atomicAdd(&deg[dst[e]], 1);
}

__global__ void k_rowptr(const int* __restrict__ deg, int* __restrict__ row_ptr,
                         int* __restrict__ cursor, float* __restrict__ inv_deg,
                         int* __restrict__ counter, int n) {
    int i = blockIdx.x * blockDim.x + threadIdx.x;
    int v = (i < n) ? deg[i] : 0;
    int lane = threadIdx.x & 63;
    int incl = v;
    #pragma unroll
    for (int off = 1; off < 64; off <<= 1) {
        int t = __shfl_up(incl, off, 64);
        if (lane >= off) incl += t;
    }
    int waveTot = __shfl(incl, 63, 64);
    int base = 0;
    if (lane == 63) base = atomicAdd(counter, waveTot);
    base = __shfl(base, 63, 64);
    int excl = incl - v;
    if (i < n) {
        int start = base + excl;
        row_ptr[i] = start;
        cursor[i]  = start;
        inv_deg[i] = (v > 0) ? (1.0f / (float)v) : 0.0f;
    }
}

__global__ void k_fill(const int* __restrict__ src, const int* __restrict__ dst,
                       int* __restrict__ cursor, int* __restrict__ csr, int E) {
    int e = blockIdx.x * blockDim.x + threadIdx.x;
    if (e < E) {
        int p = atomicAdd(&cursor[dst[e]], 1);
        csr[p] = src[e];
    }
}

// ---------------- aggregation: t = nrm(self) + inv_deg * sum nrm(nbr) ----------------

__device__ __forceinline__ float4 nrm4(float4 x, float4 a, float4 c) {
    float4 r;
    r.x = fmaxf(fmaf(a.x, x.x, c.x), 0.f);
    r.y = fmaxf(fmaf(a.y, x.y, c.y), 0.f);
    r.z = fmaxf(fmaf(a.z, x.z, c.z), 0.f);
    r.w = fmaxf(fmaf(a.w, x.w, c.w), 0.f);
    return r;
}

template<int NORM>
__global__ __launch_bounds__(256, 4) void k_agg(
    const float4* __restrict__ hin4,
    const int* __restrict__ rp, const int* __restrict__ re,
    const int* __restrict__ csr, const float* __restrict__ invd,
    const float* __restrict__ nA, const float* __restrict__ nC,
    float4* __restrict__ t4, int n)
{
    int g = blockIdx.x * blockDim.x + threadIdx.x;
    int node = g / QD;
    if (node >= n) return;
    int q = g - node * QD;
    float4 a = make_float4(0.f, 0.f, 0.f, 0.f), c = a;
    if (NORM) { a = ((const float4*)nA)[q]; c = ((const float4*)nC)[q]; }
    int e = rp[node];
    const int end = re[node];
    float ax = 0.f, ay = 0.f, az = 0.f, aw = 0.f;
    for (; e + 8 <= end; e += 8) {
        int n0 = csr[e],     n1 = csr[e + 1], n2 = csr[e + 2], n3 = csr[e + 3];
        int n4 = csr[e + 4], n5 = csr[e + 5], n6 = csr[e + 6], n7 = csr[e + 7];
        float4 x0 = hin4[(size_t)n0 * QD + q];
        float4 x1 = hin4[(size_t)n1 * QD + q];
        float4 x2 = hin4[(size_t)n2 * QD + q];
        float4 x3 = hin4[(size_t)n3 * QD + q];
        float4 x4 = hin4[(size_t)n4 * QD + q];
        float4 x5 = hin4[(size_t)n5 * QD + q];
        float4 x6 = hin4[(size_t)n6 * QD + q];
        float4 x7 = hin4[(size_t)n7 * QD + q];
        if (NORM) {
            x0 = nrm4(x0, a, c); x1 = nrm4(x1, a, c); x2 = nrm4(x2, a, c); x3 = nrm4(x3, a, c);
            x4 = nrm4(x4, a, c); x5 = nrm4(x5, a, c); x6 = nrm4(x6, a, c); x7 = nrm4(x7, a, c);
        }
        ax += (x0.x + x1.x) + (x2.x + x3.x) + ((x4.x + x5.x) + (x6.x + x7.x));
        ay += (x0.y + x1.y) + (x2.y + x3.y) + ((x4.y + x5.y) + (x6.y + x7.y));
        az += (x0.z + x1.z) + (x2.z + x3.z) + ((x4.z + x5.z) + (x6.z + x7.z));
        aw += (x0.w + x1.w) + (x2.w + x3.w) + ((x4.w + x5.w) + (x6.w + x7.w));
    }
    for (; e < end; e++) {
        int nb = csr[e];
        float4 x = hin4[(size_t)nb * QD + q];
        if (NORM) x = nrm4(x, a, c);
        ax += x.x; ay += x.y; az += x.z; aw += x.w;
    }
    float4 s = hin4[(size_t)node * QD + q];
    if (NORM) s = nrm4(s, a, c);
    float id = invd[node];
    float4 o;
    o.x = fmaf(id, ax, s.x);
    o.y = fmaf(id, ay, s.y);
    o.z = fmaf(id, az, s.z);
    o.w = fmaf(id, aw, s.w);
    t4[(size_t)node * QD + q] = o;
}

// ---------------- matmul: out = t @ W + b, W staged in LDS ----------------
// block 192 = (f:96) x (g:2). Each subgroup owns a 16-node tile; W shared in LDS.
// kc loop kept at unroll-1 (R4's full unroll caused a scratch-spill catastrophe).

template<int STATS>
__global__ __launch_bounds__(192, 2) void k_mm(
    const float* __restrict__ tin, const float* __restrict__ W,
    const float* __restrict__ bias, float* __restrict__ out,
    float* __restrict__ acc, int n)
{
    __shared__ float Wl[FD * FD];                   // 36 KB
    __shared__ __align__(16) float tl[2][16][FD];   // 12 KB
    const int tid = threadIdx.x;
    const int f = tid % FD;      // output column
    const int g = tid / FD;      // tile subgroup 0/1
    #pragma unroll
    for (int i = 0; i < 12; i++)
        ((float4*)Wl)[tid + 192 * i] = ((const float4*)W)[tid + 192 * i];
    const float bf = bias[f];
    float s = 0.f, s2 = 0.f;
    const int ntile = (n + 31) / 32;

    for (int p = blockIdx.x; p < ntile; p += gridDim.x) {
        const int base = p * 32;       // 32 nodes = 2 tiles of 16
        const float4* src4 = (const float4*)(tin + (size_t)base * FD);
        const int rem = n - base;
        const int lim4 = (rem >= 32 ? 32 : rem) * QD;
        #pragma unroll
        for (int i = 0; i < 4; i++) {
            int idx = tid + 192 * i;   // 0..767 of 768 float4
            ((float4*)tl)[idx] = (idx < lim4) ? src4[idx] : make_float4(0.f, 0.f, 0.f, 0.f);
        }
        __syncthreads();
        float o[16];
        #pragma unroll
        for (int j = 0; j < 16; j++) o[j] = 0.f;
        #pragma unroll 1
        for (int kc = 0; kc < FD; kc += 4) {
            float w0 = Wl[(kc + 0) * FD + f];
            float w1 = Wl[(kc + 1) * FD + f];
            float w2 = Wl[(kc + 2) * FD + f];
            float w3 = Wl[(kc + 3) * FD + f];
            #pragma unroll
            for (int j = 0; j < 16; j++) {
                float4 tv = *(const float4*)(&tl[g][j][kc]);   // same-addr broadcast per wave
                o[j] = fmaf(tv.w, w3, fmaf(tv.z, w2, fmaf(tv.y, w1, fmaf(tv.x, w0, o[j]))));
            }
        }
        const int nodeb = base + g * 16;
        #pragma unroll
        for (int j = 0; j < 16; j++) {
            if (nodeb + j < n) {
                float v = o[j] + bf;
                out[(size_t)(nodeb + j) * FD + f] = v;
                if (STATS) { s += v; s2 = fmaf(v, v, s2); }
            }
        }
        __syncthreads();
    }
    if (STATS) {
        atomicAdd(&acc[f], s);
        atomicAdd(&acc[FD + f], s2);
    }
}

// BN constants: a = gamma*rsqrt(var+eps), c = beta - mu*a  (1 block, FD threads)
__global__ void k_bnfin(const float* __restrict__ acc,
                        const float* __restrict__ gamma, const float* __restrict__ beta,
                        float* __restrict__ na, float* __restrict__ nc, float invN) {
    int f = threadIdx.x;
    float mu  = acc[f] * invN;
    float var = acc[FD + f] * invN - mu * mu;
    float a = gamma[f] * rsqrtf(var + 1e-5f);
    na[f] = a;
    nc[f] = beta[f] - mu * a;
}

extern "C" void kernel_launch(void* const* d_in, const int* in_sizes, int n_in,
                              void* d_out, int out_size, void* d_ws, size_t ws_size,
                              hipStream_t stream) {
    const float* feat = (const float*)d_in[0];
    const float* W1   = (const float*)d_in[1];
    const float* b1   = (const float*)d_in[2];
    const float* g1   = (const float*)d_in[3];
    const float* be1  = (const float*)d_in[4];
    const float* W2   = (const float*)d_in[5];
    const float* b2   = (const float*)d_in[6];
    const float* g2   = (const float*)d_in[7];
    const float* be2  = (const float*)d_in[8];
    const float* W3   = (const float*)d_in[9];
    const float* b3   = (const float*)d_in[10];
    const int*   src  = (const int*)d_in[11];
    const int*   dst  = (const int*)d_in[12];

    const int n = in_sizes[0] / FD;   // 50000
    const int e = in_sizes[11];       // 800000

    char* w = (char*)d_ws;
    float* A       = (float*)w; w += (size_t)n * FD * 4;
    int*   deg     = (int*)w;   w += (size_t)n * 4;
    int*   counter = (int*)w;   w += 4;
    float* acc1    = (float*)w; w += 2 * FD * 4;   // zeroed together with deg
    float* acc2    = (float*)w; w += 2 * FD * 4;
    int*   rp      = (int*)w;   w += (size_t)n * 4;
    int*   re      = (int*)w;   w += (size_t)n * 4;
    int*   csr     = (int*)w;   w += (size_t)e * 4;
    float* invd    = (float*)w; w += (size_t)n * 4;
    float* na1     = (float*)w; w += FD * 4;
    float* nc1     = (float*)w; w += FD * 4;
    float* na2     = (float*)w; w += FD * 4;
    float* nc2     = (float*)w; w += FD * 4;

    float* O = (float*)d_out;
    const float invN = 1.0f / (float)n;
    const int AGG_GRID = (n * QD + 255) / 256;

    hipMemsetAsync(deg, 0, (size_t)(n + 1 + 4 * FD) * 4, stream);
    k_degree<<<(e + 255) / 256, 256, 0, stream>>>(dst, deg, e);
    k_rowptr<<<(n + 255) / 256, 256, 0, stream>>>(deg, rp, re, invd, counter, n);
    k_fill  <<<(e + 255) / 256, 256, 0, stream>>>(src, dst, re, csr, e);

    // layer 1
    k_agg<0><<<AGG_GRID, 256, 0, stream>>>((const float4*)feat, rp, re, csr, invd,
                                           nullptr, nullptr, (float4*)A, n);
    k_mm<1><<<MMGRID, 192, 0, stream>>>(A, W1, b1, A, acc1, n);
    k_bnfin<<<1, FD, 0, stream>>>(acc1, g1, be1, na1, nc1, invN);

    // layer 2
    k_agg<1><<<AGG_GRID, 256, 0, stream>>>((const float4*)A, rp, re, csr, invd,
                                           na1, nc1, (float4*)O, n);
    k_mm<1><<<MMGRID, 192, 0, stream>>>(O, W2, b2, O, acc2, n);
    k_bnfin<<<1, FD, 0, stream>>>(acc2, g2, be2, na2, nc2, invN);

    // layer 3
    k_agg<1><<<AGG_GRID, 256, 0, stream>>>((const float4*)O, rp, re, csr, invd,
                                           na2, nc2, (float4*)A, n);
    k_mm<0><<<MMGRID, 192, 0, stream>>>(A, W3, b3, O, nullptr, n);
}

// Round 7
// 313.055 us; speedup vs baseline: 8.9013x; 1.2694x over previous
//
#include <hip/hip_runtime.h>

#define FD 96
#define NB12 12   // 16B (8-elem bf16) chunks per row

typedef float  f32x4 __attribute__((ext_vector_type(4)));
typedef short  s16x8 __attribute__((ext_vector_type(8)));

__device__ __forceinline__ unsigned short f2bf(float x) {
    unsigned u = __float_as_uint(x);
    u = (u + 0x7fffu + ((u >> 16) & 1u)) >> 16;
    return (unsigned short)u;
}
__device__ __forceinline__ float bflo(unsigned u) { return __uint_as_float(u << 16); }
__device__ __forceinline__ float bfhi(unsigned u) { return __uint_as_float(u & 0xffff0000u); }

// ---------------- CSR build ----------------

__global__ void k_degree(const int* __restrict__ dst, int* __restrict__ deg, int E) {
    int e = blockIdx.x * blockDim.x + threadIdx.x;
    if (e < E) atomicAdd(&deg[dst[e]], 1);
}

__global__ void k_rowptr(const int* __restrict__ deg, int* __restrict__ row_ptr,
                         int* __restrict__ cursor, float* __restrict__ inv_deg,
                         int* __restrict__ counter, int n) {
    int i = blockIdx.x * blockDim.x + threadIdx.x;
    int v = (i < n) ? deg[i] : 0;
    int lane = threadIdx.x & 63;
    int incl = v;
    #pragma unroll
    for (int off = 1; off < 64; off <<= 1) {
        int t = __shfl_up(incl, off, 64);
        if (lane >= off) incl += t;
    }
    int waveTot = __shfl(incl, 63, 64);
    int base = 0;
    if (lane == 63) base = atomicAdd(counter, waveTot);
    base = __shfl(base, 63, 64);
    int excl = incl - v;
    if (i < n) {
        int start = base + excl;
        row_ptr[i] = start;
        cursor[i]  = start;
        inv_deg[i] = (v > 0) ? (1.0f / (float)v) : 0.0f;
    }
}

__global__ void k_fill(const int* __restrict__ src, const int* __restrict__ dst,
                       int* __restrict__ cursor, int* __restrict__ csr, int E) {
    int e = blockIdx.x * blockDim.x + threadIdx.x;
    if (e < E) {
        int p = atomicAdd(&cursor[dst[e]], 1);
        csr[p] = src[e];
    }
}

// ---------------- fp32 -> bf16 feature convert (8 elems/thread) ----------------

__global__ void k_cvt(const float4* __restrict__ in, uint4* __restrict__ o, int n16) {
    int i = blockIdx.x * blockDim.x + threadIdx.x;
    if (i >= n16) return;
    float4 x = in[2 * i], y = in[2 * i + 1];
    uint4 r;
    r.x = (unsigned)f2bf(x.x) | ((unsigned)f2bf(x.y) << 16);
    r.y = (unsigned)f2bf(x.z) | ((unsigned)f2bf(x.w) << 16);
    r.z = (unsigned)f2bf(y.x) | ((unsigned)f2bf(y.y) << 16);
    r.w = (unsigned)f2bf(y.z) | ((unsigned)f2bf(y.w) << 16);
    o[i] = r;
}

// ---------------- W (96x96 fp32, [k][f]) -> Wt (bf16, [f][k]) ----------------

__global__ void k_wprep(const float* __restrict__ W, unsigned short* __restrict__ Wt) {
    int i = blockIdx.x * blockDim.x + threadIdx.x;   // i = k*96 + col
    if (i >= FD * FD) return;
    int col = i % FD, k = i / FD;
    Wt[col * FD + k] = f2bf(W[i]);
}

// ---------------- aggregation: t = nrm(self) + inv_deg * sum nrm(nbr), bf16 io ----------------

template<int NORM>
__global__ __launch_bounds__(256, 4) void k_agg(
    const uint4* __restrict__ h,      // bf16 rows, NB12 uint4 each
    const int* __restrict__ rp, const int* __restrict__ re,
    const int* __restrict__ csr, const float* __restrict__ invd,
    const float* __restrict__ nA, const float* __restrict__ nC,
    uint4* __restrict__ t, int n)
{
    int g = blockIdx.x * blockDim.x + threadIdx.x;
    int node = g / NB12;
    if (node >= n) return;
    int q = g - node * NB12;
    float a[8], c[8];
    if (NORM) {
        #pragma unroll
        for (int z = 0; z < 8; z++) { a[z] = nA[q * 8 + z]; c[z] = nC[q * 8 + z]; }
    }
    float acc8[8];
    #pragma unroll
    for (int z = 0; z < 8; z++) acc8[z] = 0.f;

    int e = rp[node];
    const int end = re[node];
    for (; e + 8 <= end; e += 8) {
        uint4 raw[8];
        #pragma unroll
        for (int u = 0; u < 8; u++) raw[u] = h[(size_t)csr[e + u] * NB12 + q];
        #pragma unroll
        for (int u = 0; u < 8; u++) {
            float v[8];
            v[0] = bflo(raw[u].x); v[1] = bfhi(raw[u].x);
            v[2] = bflo(raw[u].y); v[3] = bfhi(raw[u].y);
            v[4] = bflo(raw[u].z); v[5] = bfhi(raw[u].z);
            v[6] = bflo(raw[u].w); v[7] = bfhi(raw[u].w);
            #pragma unroll
            for (int z = 0; z < 8; z++) {
                float x = v[z];
                if (NORM) x = fmaxf(fmaf(a[z], x, c[z]), 0.f);
                acc8[z] += x;
            }
        }
    }
    for (; e < end; e++) {
        uint4 raw = h[(size_t)csr[e] * NB12 + q];
        float v[8];
        v[0] = bflo(raw.x); v[1] = bfhi(raw.x);
        v[2] = bflo(raw.y); v[3] = bfhi(raw.y);
        v[4] = bflo(raw.z); v[5] = bfhi(raw.z);
        v[6] = bflo(raw.w); v[7] = bfhi(raw.w);
        #pragma unroll
        for (int z = 0; z < 8; z++) {
            float x = v[z];
            if (NORM) x = fmaxf(fmaf(a[z], x, c[z]), 0.f);
            acc8[z] += x;
        }
    }
    // self
    uint4 rs = h[(size_t)node * NB12 + q];
    float xs[8];
    xs[0] = bflo(rs.x); xs[1] = bfhi(rs.x);
    xs[2] = bflo(rs.y); xs[3] = bfhi(rs.y);
    xs[4] = bflo(rs.z); xs[5] = bfhi(rs.z);
    xs[6] = bflo(rs.w); xs[7] = bfhi(rs.w);
    float id = invd[node];
    float o[8];
    #pragma unroll
    for (int z = 0; z < 8; z++) {
        float x = xs[z];
        if (NORM) x = fmaxf(fmaf(a[z], x, c[z]), 0.f);
        o[z] = fmaf(id, acc8[z], x);
    }
    uint4 pk;
    pk.x = (unsigned)f2bf(o[0]) | ((unsigned)f2bf(o[1]) << 16);
    pk.y = (unsigned)f2bf(o[2]) | ((unsigned)f2bf(o[3]) << 16);
    pk.z = (unsigned)f2bf(o[4]) | ((unsigned)f2bf(o[5]) << 16);
    pk.w = (unsigned)f2bf(o[6]) | ((unsigned)f2bf(o[7]) << 16);
    t[(size_t)node * NB12 + q] = pk;
}

// ---------------- MFMA matmul: y = t @ W + b ----------------
// block = 256 (4 waves); each wave does a 16-row x 96-col tile via 6 coltiles x 3 ksteps.
// A frag: t[row=lane&15][k0 = 32s + 8*(lane>>4) ..+7]; B frag: Wt[col=lane&15][k0..+7].
// C/D: col = lane&15, row = (lane>>4)*4 + reg.

template<int STATS, int OBF>
__global__ void k_mm(const unsigned short* __restrict__ ta,
                     const unsigned short* __restrict__ Wt,
                     const float* __restrict__ bias,
                     unsigned short* __restrict__ yb, float* __restrict__ yf,
                     float* __restrict__ accg, int n)
{
    __shared__ float sred[2 * FD];
    const int tid  = threadIdx.x;
    const int lane = tid & 63;
    const int wv   = tid >> 6;
    const int colb = lane & 15;
    const int hg   = lane >> 4;
    const int rbase = blockIdx.x * 64 + wv * 16;
    const int r = rbase + colb;

    s16x8 a[3];
    if (r < n) {
        #pragma unroll
        for (int s = 0; s < 3; s++)
            a[s] = *reinterpret_cast<const s16x8*>(ta + (size_t)r * FD + s * 32 + hg * 8);
    } else {
        #pragma unroll
        for (int s = 0; s < 3; s++) a[s] = s16x8{0, 0, 0, 0, 0, 0, 0, 0};
    }
    s16x8 b[6][3];
    #pragma unroll
    for (int c2 = 0; c2 < 6; c2++)
        #pragma unroll
        for (int s = 0; s < 3; s++)
            b[c2][s] = *reinterpret_cast<const s16x8*>(Wt + (size_t)(c2 * 16 + colb) * FD + s * 32 + hg * 8);

    f32x4 acc[6];
    #pragma unroll
    for (int c2 = 0; c2 < 6; c2++) acc[c2] = (f32x4){0.f, 0.f, 0.f, 0.f};
    #pragma unroll
    for (int s = 0; s < 3; s++)
        #pragma unroll
        for (int c2 = 0; c2 < 6; c2++)
            acc[c2] = __builtin_amdgcn_mfma_f32_16x16x32_bf16(a[s], b[c2][s], acc[c2], 0, 0, 0);

    float s1[6], s2[6];
    #pragma unroll
    for (int c2 = 0; c2 < 6; c2++) { s1[c2] = 0.f; s2[c2] = 0.f; }
    #pragma unroll
    for (int c2 = 0; c2 < 6; c2++) {
        float bc = bias[c2 * 16 + colb];
        #pragma unroll
        for (int j = 0; j < 4; j++) {
            int rr = rbase + hg * 4 + j;
            if (rr < n) {
                float y = acc[c2][j] + bc;
                if (OBF) yb[(size_t)rr * FD + c2 * 16 + colb] = f2bf(y);
                else     yf[(size_t)rr * FD + c2 * 16 + colb] = y;
                if (STATS) { s1[c2] += y; s2[c2] = fmaf(y, y, s2[c2]); }
            }
        }
    }
    if (STATS) {
        if (tid < 2 * FD) sred[tid] = 0.f;
        __syncthreads();
        #pragma unroll
        for (int c2 = 0; c2 < 6; c2++) {
            float v1 = s1[c2], v2 = s2[c2];
            v1 += __shfl_xor(v1, 16, 64); v1 += __shfl_xor(v1, 32, 64);
            v2 += __shfl_xor(v2, 16, 64); v2 += __shfl_xor(v2, 32, 64);
            if (lane < 16) {
                atomicAdd(&sred[c2 * 16 + colb], v1);
                atomicAdd(&sred[FD + c2 * 16 + colb], v2);
            }
        }
        __syncthreads();
        if (tid < 2 * FD) atomicAdd(&accg[tid], sred[tid]);
    }
}

// BN constants: a = gamma*rsqrt(var+eps), c = beta - mu*a
__global__ void k_bnfin(const float* __restrict__ acc,
                        const float* __restrict__ gamma, const float* __restrict__ beta,
                        float* __restrict__ na, float* __restrict__ nc, float invN) {
    int f = threadIdx.x;
    float mu  = acc[f] * invN;
    float var = acc[FD + f] * invN - mu * mu;
    float a = gamma[f] * rsqrtf(var + 1e-5f);
    na[f] = a;
    nc[f] = beta[f] - mu * a;
}

extern "C" void kernel_launch(void* const* d_in, const int* in_sizes, int n_in,
                              void* d_out, int out_size, void* d_ws, size_t ws_size,
                              hipStream_t stream) {
    const float* feat = (const float*)d_in[0];
    const float* W1   = (const float*)d_in[1];
    const float* b1   = (const float*)d_in[2];
    const float* g1   = (const float*)d_in[3];
    const float* be1  = (const float*)d_in[4];
    const float* W2   = (const float*)d_in[5];
    const float* b2   = (const float*)d_in[6];
    const float* g2   = (const float*)d_in[7];
    const float* be2  = (const float*)d_in[8];
    const float* W3   = (const float*)d_in[9];
    const float* b3   = (const float*)d_in[10];
    const int*   src  = (const int*)d_in[11];
    const int*   dst  = (const int*)d_in[12];

    const int n = in_sizes[0] / FD;   // 50000
    const int e = in_sizes[11];       // 800000

    char* w = (char*)d_ws;
    unsigned short* hf0 = (unsigned short*)w; w += (size_t)n * FD * 2;   // features bf16
    unsigned short* tb  = (unsigned short*)w; w += (size_t)n * FD * 2;   // t buffer bf16
    unsigned short* Wt1 = (unsigned short*)w; w += FD * FD * 2;
    unsigned short* Wt2 = (unsigned short*)w; w += FD * FD * 2;
    unsigned short* Wt3 = (unsigned short*)w; w += FD * FD * 2;
    int*   csr     = (int*)w;   w += (size_t)e * 4;
    int*   deg     = (int*)w;   w += (size_t)n * 4;
    int*   counter = (int*)w;   w += 4;
    float* acc1    = (float*)w; w += 2 * FD * 4;   // zeroed with deg
    float* acc2    = (float*)w; w += 2 * FD * 4;
    int*   rp      = (int*)w;   w += (size_t)n * 4;
    int*   re      = (int*)w;   w += (size_t)n * 4;
    float* invd    = (float*)w; w += (size_t)n * 4;
    float* na1     = (float*)w; w += FD * 4;
    float* nc1     = (float*)w; w += FD * 4;
    float* na2     = (float*)w; w += FD * 4;
    float* nc2     = (float*)w; w += FD * 4;

    unsigned short* yb = (unsigned short*)d_out;   // bf16 y lives inside d_out
    float* O = (float*)d_out;
    const float invN = 1.0f / (float)n;
    const int AGG_GRID = (n * NB12 + 255) / 256;
    const int MM_GRID  = (n + 63) / 64;
    const int n16 = n * FD / 8;

    hipMemsetAsync(deg, 0, (size_t)n * 4 + 4 + 4 * FD * 4, stream);
    k_cvt<<<(n16 + 255) / 256, 256, 0, stream>>>((const float4*)feat, (uint4*)hf0, n16);
    k_wprep<<<(FD * FD + 255) / 256, 256, 0, stream>>>(W1, Wt1);
    k_wprep<<<(FD * FD + 255) / 256, 256, 0, stream>>>(W2, Wt2);
    k_wprep<<<(FD * FD + 255) / 256, 256, 0, stream>>>(W3, Wt3);
    k_degree<<<(e + 255) / 256, 256, 0, stream>>>(dst, deg, e);
    k_rowptr<<<(n + 255) / 256, 256, 0, stream>>>(deg, rp, re, invd, counter, n);
    k_fill  <<<(e + 255) / 256, 256, 0, stream>>>(src, dst, re, csr, e);

    // layer 1
    k_agg<0><<<AGG_GRID, 256, 0, stream>>>((const uint4*)hf0, rp, re, csr, invd,
                                           nullptr, nullptr, (uint4*)tb, n);
    k_mm<1, 1><<<MM_GRID, 256, 0, stream>>>(tb, Wt1, b1, yb, nullptr, acc1, n);
    k_bnfin<<<1, FD, 0, stream>>>(acc1, g1, be1, na1, nc1, invN);

    // layer 2
    k_agg<1><<<AGG_GRID, 256, 0, stream>>>((const uint4*)yb, rp, re, csr, invd,
                                           na1, nc1, (uint4*)tb, n);
    k_mm<1, 1><<<MM_GRID, 256, 0, stream>>>(tb, Wt2, b2, yb, nullptr, acc2, n);
    k_bnfin<<<1, FD, 0, stream>>>(acc2, g2, be2, na2, nc2, invN);

    // layer 3
    k_agg<1><<<AGG_GRID, 256, 0, stream>>>((const uint4*)yb, rp, re, csr, invd,
                                           na2, nc2, (uint4*)tb, n);
    k_mm<0, 0><<<MM_GRID, 256, 0, stream>>>(tb, Wt3, b3, nullptr, O, nullptr, n);
}